// Round 12
// baseline (499.740 us; speedup 1.0000x reference)
//
#include <hip/hip_runtime.h>
#include <hip/hip_bf16.h>

// FastUpConvolution on MI355X — round 19: W bypasses LDS entirely.
// A-fragments load DIRECT from global (L2-resident W panel) into registers;
// only X is LDS-staged. Deletes the W triple-buffer, all WAITBAR machinery,
// and the per-tap barrier: tap loop is barrier-free (2 plain __syncthreads
// per chunk for the X buffer WAR/RAW). Compiler software-pipelines the 8
// 16B W loads per tap across the fully-unrolled tap loop.
//
// R18 post-mortem: gemm plateau ~142us, MfmaUtil 39. LDS frag-read demand
// ~75us/CU is the binding pipe; W staging is half of it yet each W byte is
// DMA'd once and read only TWICE (2 waves share wn) -> direct L2 reads are
// cheaper. New pipe budget/CU: MFMA ~55us, LDS ~37 (X only) + ~12 DMA,
// W via L2 ~57us chip-wide -> overlapped, barrier-free. VGPR ~125-150,
// __launch_bounds__(256,3) -> 3 blocks/CU (was 2). Pre-registered failure
// signatures: scratch>0 (spill); MfmaUtil<40 same-dur (latency unhidden);
// FETCH>>100MB (L2 thrash).
//
// ws layout:
//   x_t   : bf16 [16][34][34][512]  @ 0          (18,939,904 B)
//   W_t   : bf16 [1024 rows][9*512] @ 18,939,904 ( 9,437,184 B)  row=pair-ilv
//   bias  : f32  [1024]             @ 28,377,088 (     4,096 B)  row=pair-ilv
//   stats : f32  [512] sum|sumsq    @ 28,381,184 (     2,048 B)
//
// Row layout: row' = ((q&1)<<9) + co*2 + (q>>1):
//   P0 rows 0..511   : q0 (3x3) s=0, q2 (3x2) s=1  -> even output rows, 9 taps
//   P1 rows 512..1023: q1 (2x3) s=0, q3 (2x2) s=1  -> odd output rows, 6 taps

typedef unsigned short ushort_t;
typedef __attribute__((ext_vector_type(8))) short short8;
typedef __attribute__((ext_vector_type(4))) float floatx4;
typedef __attribute__((ext_vector_type(2))) float floatx2;
typedef __attribute__((ext_vector_type(4))) unsigned short u16x4;
typedef __attribute__((ext_vector_type(8))) unsigned short u16x8;
typedef __attribute__((ext_vector_type(4))) unsigned int u32x4;

#define XT_OFF    0u
#define WT_OFF    18939904u
#define BIAS_OFF  28377088u
#define STATS_OFF 28381184u

#define NSITES_P0 204         // 6 rows x 34 cols X footprint, 128 B per site
#define NSITES_P1 170         // 5 rows x 34 cols (taps 0..5 only)

#define ASYNC16(g, l) __builtin_amdgcn_global_load_lds( \
    (const __attribute__((address_space(1))) void*)(g), \
    (__attribute__((address_space(3))) void*)(l), 16, 0, 0)

__device__ __forceinline__ ushort_t f2bf(float f) {
  unsigned int u = __builtin_bit_cast(unsigned int, f);
  u += 0x7fffu + ((u >> 16) & 1u);   // RNE (values finite here)
  return (ushort_t)(u >> 16);
}

// --------------------------------------------------------------- prep_all --
// Blocks 0..1023: W prep (block 0 also zeroes stats).
// Blocks 1024..3199: X prep, one block per (n, hp, ci-quarter):
//   x[16][512][32][32] f32 -> x_t[16][34][34][512] bf16, zero-padded NHWC.
__global__ __launch_bounds__(256) void prep_all(
    const float* __restrict__ x, ushort_t* __restrict__ xt,
    const float* __restrict__ w1, const float* __restrict__ w2,
    const float* __restrict__ w3, const float* __restrict__ w4,
    const float* __restrict__ b1, const float* __restrict__ b2,
    const float* __restrict__ b3, const float* __restrict__ b4,
    ushort_t* __restrict__ wt, float* __restrict__ bias,
    float* __restrict__ stats) {
  __shared__ ushort_t lds[128 * 36];   // 9,216 B
  const int blk = blockIdx.x;
  const int t = threadIdx.x;
  if (blk < 1024) {
    // ---------------- W prep ----------------
    const int q = blk >> 8, co = blk & 255;
    const int row = ((q & 1) << 9) + (co << 1) + (q >> 1);  // pair-interleaved
    if (blk == 0) { stats[t] = 0.f; stats[t + 256] = 0.f; }
    const float* wsrc; const float* bsrc; int khl, kwl;
    if (q == 0)      { wsrc = w1; bsrc = b1; khl = 3; kwl = 3; }
    else if (q == 1) { wsrc = w2; bsrc = b2; khl = 2; kwl = 3; }
    else if (q == 2) { wsrc = w3; bsrc = b3; khl = 3; kwl = 2; }
    else             { wsrc = w4; bsrc = b4; khl = 2; kwl = 2; }
    if (t == 0) bias[row] = bsrc[co];
    ushort_t* dst = wt + (size_t)row * 4608;
    for (int tap = 0; tap < 9; ++tap) {
      const int dh = tap / 3, dw = tap % 3;
      const bool valid = (dh < khl) && (dw < kwl);
#pragma unroll
      for (int cc = 0; cc < 2; ++cc) {
        const int ci = cc * 256 + t;
        ushort_t v = 0;
        if (valid)
          v = f2bf(wsrc[(((size_t)co * 512 + ci) * khl + dh) * kwl + dw]);
        dst[tap * 512 + ci] = v;
      }
    }
    return;
  }
  // ---------------- X prep (quarter) ----------------
  const int idx = blk - 1024;
  const int n = idx / 136;            // 136 = 34 hp * 4 quarters
  const int rem = idx % 136;
  const int hp = rem >> 2;
  const int ci0 = (rem & 3) << 7;     // 0,128,256,384
  ushort_t* dst = xt + (size_t)(n * 34 + hp) * (34 * 512);
  if (hp == 0 || hp == 33) {
    u32x4 z = {0u, 0u, 0u, 0u};
    for (int i = t; i < 544; i += 256)
      ((u32x4*)(dst + (i >> 4) * 512 + ci0))[i & 15] = z;
    return;
  }
  const int h = hp - 1;
  if (t < 32) {
    u32x4 z = {0u, 0u, 0u, 0u};
    const int w = (t >> 4) ? 33 : 0;
    ((u32x4*)(dst + w * 512 + ci0))[t & 15] = z;
  }
  const size_t base = (size_t)n * 524288 + (size_t)h * 32;
  {
    const int cil = t >> 3;
    const int w4 = (t & 7) << 2;
#pragma unroll
    for (int cc = 0; cc < 4; ++cc) {
      const int ci = cil + cc * 32;
      floatx4 v = *(const floatx4*)(x + base + (size_t)(ci0 + ci) * 1024 + w4);
      u16x4 hv;
#pragma unroll
      for (int j = 0; j < 4; ++j) hv[j] = f2bf(v[j]);
      *(u16x4*)&lds[ci * 36 + w4] = hv;
    }
  }
  __syncthreads();
  {
    const int w = t & 31;
    const int j8 = t >> 5;
#pragma unroll
    for (int cc2 = 0; cc2 < 2; ++cc2) {
      const int cil2 = cc2 * 64 + j8 * 8;
      u16x8 v;
#pragma unroll
      for (int j = 0; j < 8; ++j) v[j] = lds[(cil2 + j) * 36 + w];
      *(u16x8*)(dst + (w + 1) * 512 + ci0 + cil2) = v;
    }
  }
}

// ------------------------------------------------------------- gemm body ---
// Block 128 m (4h x 32w) x 128 n; 4 waves 2x2, 4x4 frags of 16x16x32 bf16.
// K = 8 chunks x 64 ci x NTAPS (compile-time: P0 9, P1 6).
// Per chunk: __syncthreads (WAR) -> ASYNC16-stage X footprint ->
// __syncthreads (drains vmcnt: X visible) -> BARRIER-FREE tap loop:
//   per tap: 8x global_load_dwordx4 W A-frags (L2-resident panel, compiler
//   pipelines across unrolled taps), 2 k-steps x (4 swizzled ldsX reads,
//   16 MFMA). LDS: X only, XOR-swizzled c^(srow&7).
template <int NTAPS, int NSITES_T>
__device__ __forceinline__ void gemm_body(
    const ushort_t* __restrict__ xt, const ushort_t* __restrict__ wt,
    const float* __restrict__ bias, float* __restrict__ out,
    float* __restrict__ stats, char* ldsX, int bn, int bm) {
  const int tid = threadIdx.x;
  const int n0 = bn << 7;
  const int n_img = bm >> 3;
  const int h0p = (bm & 7) << 2;        // first padded x_t row of footprint
  const int wv = tid >> 6, lane = tid & 63;
  const int ri = lane & 15, kg = lane >> 4;
  const int wm = (wv & 1) << 6, wn = (wv >> 1) << 6;

  constexpr int XTOT = NSITES_T * 8;    // 16B loads for X footprint
  constexpr int XFP = XTOT / 256;       // full 256-thread passes
  constexpr int XTL = XTOT - XFP * 256; // tail threads

  // ---- X staging pointers (XOR swizzle at issue) ----
  const char* xgp[XFP + 1];
  char* xlp[XFP + 1];
  {
    const char* xg = (const char*)(xt + (size_t)(n_img * 34 + h0p) * (34 * 512));
#pragma unroll
    for (int p = 0; p < XFP + 1; ++p) {
      const int idx = p * 256 + tid;
      const int site = idx >> 3, slot = idx & 7;
      const int c = slot ^ (site & 7);
      xgp[p] = xg + site * 1024 + (c << 4);
      xlp[p] = ldsX + idx * 16;
    }
  }
  // ---- W direct-load byte offsets for the 4 A-frag rows ----
  const char* wbase = (const char*)wt;
  unsigned int wrow[4];
#pragma unroll
  for (int f = 0; f < 4; ++f)
    wrow[f] = (unsigned int)(n0 + wn + (f << 4) + ri) * 9216u;

  floatx4 acc[4][4] = {};

  int bsite[4];
#pragma unroll
  for (int fj = 0; fj < 4; ++fj)
    bsite[fj] = ((wm >> 5) + (fj >> 1)) * 34 + ((fj & 1) << 4) + ri;

  for (int chunk = 0; chunk < 8; ++chunk) {
    const int cb = chunk << 7;
    __syncthreads();   // WAR: all waves done reading previous chunk's X
#pragma unroll
    for (int p = 0; p < XFP; ++p) ASYNC16(xgp[p] + cb, xlp[p]);
    if (tid < XTL) ASYNC16(xgp[XFP] + cb, xlp[XFP]);   // tail
    __syncthreads();   // implicit vmcnt(0) drain: X resident & visible
#pragma unroll
    for (int tap = 0; tap < NTAPS; ++tap) {
      const unsigned int toff = (unsigned int)(tap << 10) + cb;
      const int tsite = (tap / 3) * 34 + (tap % 3);   // X site offset of tap
      // A-frags direct from global (no swizzle; exact 16B chunks).
      short8 aw[2][4];
#pragma unroll
      for (int ks = 0; ks < 2; ++ks)
#pragma unroll
        for (int f = 0; f < 4; ++f)
          aw[ks][f] = *(const short8*)(
              wbase + wrow[f] + toff + (((ks << 2) + kg) << 4));
#pragma unroll
      for (int ks = 0; ks < 2; ++ks) {
        const int c = (ks << 2) + kg;    // 16B chunk index within row
        short8 b4[4];
#pragma unroll
        for (int fj = 0; fj < 4; ++fj) {
          const int srow = bsite[fj] + tsite;   // shifted site; swizzle on it
          b4[fj] = *(const short8*)(ldsX + srow * 128 + ((c ^ (srow & 7)) << 4));
        }
#pragma unroll
        for (int fi = 0; fi < 4; ++fi)
#pragma unroll
          for (int fj = 0; fj < 4; ++fj)
            acc[fi][fj] = __builtin_amdgcn_mfma_f32_16x16x32_bf16(
                aw[ks][fi], b4[fj], acc[fi][fj], 0, 0, 0);
      }
    }
  }

  // ---- epilogue: +bias, dense 2x2 pixel-shuffle writes, fused BN stats ----
  // D layout: col=lane&15 (m), row=quad*4+reg (n). Pair-interleaved rows:
  // (j0,j1) = same co, cols 2w/2w+1 -> contiguous floatx2; (j2,j3) = co+1.
  // Output row parity: P0 (bn<4) -> even rows; P1 -> odd rows.
  const int quad = kg, colL = ri;
  const int dh6 = (bn >> 2) << 6;       // +64 floats for odd output rows
#pragma unroll
  for (int fi = 0; fi < 4; ++fi) {
    const int rbase = n0 + wn + (fi << 4) + (quad << 2);   // global row', j=0..3
    const floatx4 bv = *(const floatx4*)(bias + rbase);
    const int co = (rbase & 511) >> 1;
    float sA = 0.f, s2A = 0.f, sB = 0.f, s2B = 0.f;
    float* ob = out + (((size_t)(n_img * 256 + co)) << 12) + dh6;
#pragma unroll
    for (int fj = 0; fj < 4; ++fj) {
      const int mb = wm + (fj << 4) + colL;       // m within block
      const int h = h0p + (mb >> 5), w = mb & 31; // global h (0..31)
      const float v0 = acc[fi][fj][0] + bv[0];
      const float v1 = acc[fi][fj][1] + bv[1];
      const float v2 = acc[fi][fj][2] + bv[2];
      const float v3 = acc[fi][fj][3] + bv[3];
      sA += v0 + v1;
      s2A += v0 * v0 + v1 * v1;
      sB += v2 + v3;
      s2B += v2 * v2 + v3 * v3;
      float* p = ob + (h << 7) + (w << 1);        // row 2h(+dh), col 2w
      floatx2 eA = {v0, v1};
      floatx2 eB = {v2, v3};
      *(floatx2*)p = eA;                           // co
      *(floatx2*)(p + 4096) = eB;                  // co+1
    }
#pragma unroll
    for (int off = 1; off < 16; off <<= 1) {
      sA += __shfl_xor(sA, off);
      s2A += __shfl_xor(s2A, off);
      sB += __shfl_xor(sB, off);
      s2B += __shfl_xor(s2B, off);
    }
    if (colL == 0) {
      atomicAdd(&stats[co], sA);
      atomicAdd(&stats[256 + co], s2A);
      atomicAdd(&stats[co + 1], sB);
      atomicAdd(&stats[256 + co + 1], s2B);
    }
  }
}

__global__ __launch_bounds__(256, 3) void gemm_kernel(
    const ushort_t* __restrict__ xt, const ushort_t* __restrict__ wt,
    const float* __restrict__ bias, float* __restrict__ out,
    float* __restrict__ stats) {
  // LDS: X only (26,112 B) -> LDS allows 6 blocks/CU; VGPR is the limiter.
  __shared__ char ldsX[NSITES_P0 * 128];
  const int bx = blockIdx.x;
  // Panel flip at the grid midpoint: each XCD (bx&7 under round-robin
  // dispatch) runs 64 blocks of panel k, then 64 of panel k^4 -> per-XCD
  // 9-tap/6-tap totals balanced; <=2 W panels live per XCD L2 (W panel
  // residency now carries the A-operand reads directly).
  const int bn = (bx & 7) ^ (((bx >> 9) & 1) << 2);
  const int bm = (bx >> 3) & 127;
  if (bn < 4)
    gemm_body<9, NSITES_P0>(xt, wt, bias, out, stats, ldsX, bn, bm);
  else
    gemm_body<6, NSITES_P1>(xt, wt, bias, out, stats, ldsX, bn, bm);
}

// -------------------------------------------------------------- bn_apply ---
__global__ __launch_bounds__(256) void bn_apply(
    float* __restrict__ y, const float* __restrict__ stats,
    const float* __restrict__ gamma, const float* __restrict__ beta) {
  const int b = blockIdx.x;
  const int co = b & 255;
  const int t = threadIdx.x;
  const float mean = stats[co] * (1.f / 65536.f);
  const float var = stats[256 + co] * (1.f / 65536.f) - mean * mean;
  const float rstd = rsqrtf(var + 1e-5f);
  const float scale = rstd * gamma[co];
  const float shift = beta[co] - mean * scale;
  float* p = y + (size_t)b * 4096;
#pragma unroll
  for (int it = 0; it < 4; ++it) {
    floatx4* q = (floatx4*)(p + (it * 256 + t) * 4);
    floatx4 v = *q;
#pragma unroll
    for (int e = 0; e < 4; ++e) v[e] = fmaxf(v[e] * scale + shift, 0.f);
    *q = v;
  }
}

// ---------------------------------------------------------------- launch ---
extern "C" void kernel_launch(void* const* d_in, const int* in_sizes, int n_in,
                              void* d_out, int out_size, void* d_ws,
                              size_t ws_size, hipStream_t stream) {
  const float* x  = (const float*)d_in[0];
  const float* w1 = (const float*)d_in[1];
  const float* b1 = (const float*)d_in[2];
  const float* w2 = (const float*)d_in[3];
  const float* b2 = (const float*)d_in[4];
  const float* w3 = (const float*)d_in[5];
  const float* b3 = (const float*)d_in[6];
  const float* w4 = (const float*)d_in[7];
  const float* b4 = (const float*)d_in[8];
  const float* gamma = (const float*)d_in[9];
  const float* beta  = (const float*)d_in[10];
  float* out = (float*)d_out;

  char* ws = (char*)d_ws;
  ushort_t* xt   = (ushort_t*)(ws + XT_OFF);
  ushort_t* wt   = (ushort_t*)(ws + WT_OFF);
  float*    bias = (float*)(ws + BIAS_OFF);
  float*    st   = (float*)(ws + STATS_OFF);

  prep_all<<<3200, 256, 0, stream>>>(x, xt, w1, w2, w3, w4,
                                     b1, b2, b3, b4, wt, bias, st);
  gemm_kernel<<<1024, 256, 0, stream>>>(xt, wt, bias, out, st);
  bn_apply<<<4096, 256, 0, stream>>>(out, st, gamma, beta);
}

// Round 13
// 309.482 us; speedup vs baseline: 1.6148x; 1.6148x over previous
//
#include <hip/hip_runtime.h>
#include <hip/hip_bf16.h>

// FastUpConvolution on MI355X — round 20: W direct-from-L2 in FRAGMENT-MAJOR
// layout + explicit register double-buffer. R19's concept (W never touches
// LDS; each staged W byte was read only 2x) with its two failure causes
// fixed:
//  (1) R19 scatter: A-frag load had ri on the ROW index (stride 9216B) ->
//      64x16B scattered per wave -> L2 thrash (FETCH 82->208MB, WRITE
//      67->118MB). NOW: prep_w stores W'[g][tap][chunk16B][ri] so a wave's
//      frag load is contiguous 1KB (lane l=kg*16+ri reads kg*256+ri*16).
//  (2) R19 VGPR=84: compiler serially reloaded W (no pipelining). NOW:
//      aw[2][2][4] register double-buffer, tap t+1's 8 coalesced loads
//      issued before tap t's MFMAs (fully-unrolled loop, static indices).
// LDS holds X only (26KB): port demand ~102 -> ~44us/CU; MFMA (~55us)
// becomes max pipe; W served by XCD-pinned L2 panel (~2GB chip-wide).
// Barriers: 2 plain __syncthreads per chunk. __launch_bounds__(256,2)
// (spill is worse than low occupancy; est ~180 VGPR).
// Pre-registered failure: FETCH>120MB or scratch>0 -> revert R18, plateau.
//
// ws layout:
//   x_t   : bf16 [16][34][34][512]  @ 0          (18,939,904 B)
//   W_t   : bf16 frag-major [64 g][9 tap][64 c16][16 ri] @ 18,939,904
//           (9,437,184 B) — g = row'>>4, ri = row'&15, row' pair-interleaved
//   bias  : f32  [1024]             @ 28,377,088 (     4,096 B)  row=pair-ilv
//   stats : f32  [512] sum|sumsq    @ 28,381,184 (     2,048 B)
//
// Row' = ((q&1)<<9) + co*2 + (q>>1):
//   P0 rows 0..511   : q0 (3x3) s=0, q2 (3x2) s=1  -> even output rows, 9 taps
//   P1 rows 512..1023: q1 (2x3) s=0, q3 (2x2) s=1  -> odd output rows, 6 taps

typedef unsigned short ushort_t;
typedef __attribute__((ext_vector_type(8))) short short8;
typedef __attribute__((ext_vector_type(4))) float floatx4;
typedef __attribute__((ext_vector_type(2))) float floatx2;
typedef __attribute__((ext_vector_type(4))) unsigned short u16x4;
typedef __attribute__((ext_vector_type(8))) unsigned short u16x8;
typedef __attribute__((ext_vector_type(4))) unsigned int u32x4;

#define XT_OFF    0u
#define WT_OFF    18939904u
#define BIAS_OFF  28377088u
#define STATS_OFF 28381184u

#define NSITES_P0 204         // 6 rows x 34 cols X footprint, 128 B per site
#define NSITES_P1 170         // 5 rows x 34 cols (taps 0..5 only)

#define ASYNC16(g, l) __builtin_amdgcn_global_load_lds( \
    (const __attribute__((address_space(1))) void*)(g), \
    (__attribute__((address_space(3))) void*)(l), 16, 0, 0)

__device__ __forceinline__ ushort_t f2bf(float f) {
  unsigned int u = __builtin_bit_cast(unsigned int, f);
  u += 0x7fffu + ((u >> 16) & 1u);   // RNE (values finite here)
  return (ushort_t)(u >> 16);
}

// --------------------------------------------------------------- prep_all --
// Blocks 0..1023: W prep into FRAGMENT-MAJOR layout (block 0 zeroes stats).
//   ushort index for (g,rr,tap,ci): g*73728 + tap*8192 + (ci>>3)*128
//                                   + rr*8 + (ci&7).
// Blocks 1024..3199: X prep, one block per (n, hp, ci-quarter).
__global__ __launch_bounds__(256) void prep_all(
    const float* __restrict__ x, ushort_t* __restrict__ xt,
    const float* __restrict__ w1, const float* __restrict__ w2,
    const float* __restrict__ w3, const float* __restrict__ w4,
    const float* __restrict__ b1, const float* __restrict__ b2,
    const float* __restrict__ b3, const float* __restrict__ b4,
    ushort_t* __restrict__ wt, float* __restrict__ bias,
    float* __restrict__ stats) {
  __shared__ ushort_t lds[128 * 36];   // 9,216 B
  const int blk = blockIdx.x;
  const int t = threadIdx.x;
  if (blk < 1024) {
    // ---------------- W prep ----------------
    const int q = blk >> 8, co = blk & 255;
    const int row = ((q & 1) << 9) + (co << 1) + (q >> 1);  // pair-interleaved
    const int g = row >> 4, rr = row & 15;
    if (blk == 0) { stats[t] = 0.f; stats[t + 256] = 0.f; }
    const float* wsrc; const float* bsrc; int khl, kwl;
    if (q == 0)      { wsrc = w1; bsrc = b1; khl = 3; kwl = 3; }
    else if (q == 1) { wsrc = w2; bsrc = b2; khl = 2; kwl = 3; }
    else if (q == 2) { wsrc = w3; bsrc = b3; khl = 3; kwl = 2; }
    else             { wsrc = w4; bsrc = b4; khl = 2; kwl = 2; }
    if (t == 0) bias[row] = bsrc[co];
    ushort_t* dst = wt + (size_t)g * 73728 + rr * 8;
    for (int tap = 0; tap < 9; ++tap) {
      const int dh = tap / 3, dw = tap % 3;
      const bool valid = (dh < khl) && (dw < kwl);
#pragma unroll
      for (int cc = 0; cc < 2; ++cc) {
        const int ci = cc * 256 + t;
        ushort_t v = 0;
        if (valid)
          v = f2bf(wsrc[(((size_t)co * 512 + ci) * khl + dh) * kwl + dw]);
        dst[tap * 8192 + (ci >> 3) * 128 + (ci & 7)] = v;
      }
    }
    return;
  }
  // ---------------- X prep (quarter) ----------------
  const int idx = blk - 1024;
  const int n = idx / 136;            // 136 = 34 hp * 4 quarters
  const int rem = idx % 136;
  const int hp = rem >> 2;
  const int ci0 = (rem & 3) << 7;     // 0,128,256,384
  ushort_t* dst = xt + (size_t)(n * 34 + hp) * (34 * 512);
  if (hp == 0 || hp == 33) {
    u32x4 z = {0u, 0u, 0u, 0u};
    for (int i = t; i < 544; i += 256)
      ((u32x4*)(dst + (i >> 4) * 512 + ci0))[i & 15] = z;
    return;
  }
  const int h = hp - 1;
  if (t < 32) {
    u32x4 z = {0u, 0u, 0u, 0u};
    const int w = (t >> 4) ? 33 : 0;
    ((u32x4*)(dst + w * 512 + ci0))[t & 15] = z;
  }
  const size_t base = (size_t)n * 524288 + (size_t)h * 32;
  {
    const int cil = t >> 3;
    const int w4 = (t & 7) << 2;
#pragma unroll
    for (int cc = 0; cc < 4; ++cc) {
      const int ci = cil + cc * 32;
      floatx4 v = *(const floatx4*)(x + base + (size_t)(ci0 + ci) * 1024 + w4);
      u16x4 hv;
#pragma unroll
      for (int j = 0; j < 4; ++j) hv[j] = f2bf(v[j]);
      *(u16x4*)&lds[ci * 36 + w4] = hv;
    }
  }
  __syncthreads();
  {
    const int w = t & 31;
    const int j8 = t >> 5;
#pragma unroll
    for (int cc2 = 0; cc2 < 2; ++cc2) {
      const int cil2 = cc2 * 64 + j8 * 8;
      u16x8 v;
#pragma unroll
      for (int j = 0; j < 8; ++j) v[j] = lds[(cil2 + j) * 36 + w];
      *(u16x8*)(dst + (w + 1) * 512 + ci0 + cil2) = v;
    }
  }
}

// ------------------------------------------------------------- gemm body ---
// Block 128 m (4h x 32w) x 128 n; 4 waves 2x2, 4x4 frags of 16x16x32 bf16.
// K = 8 chunks x 64 ci x NTAPS (compile-time: P0 9, P1 6).
// Per chunk: issue tap0's 8 coalesced W loads (regs) -> __syncthreads (WAR)
// -> ASYNC16-stage X -> __syncthreads (vmcnt drain) -> barrier-free tap
// loop: issue tap+1's W loads into aw[(tap+1)&1], compute 2 ks x (4 swizzled
// ldsX reads, 16 MFMA) on aw[tap&1]. W frag load = contiguous 1KB/wave:
// wp[f] + tap*16384 + chunk*2048 + ks*1024 (+kg*256+ri*16 baked into wp).
template <int NTAPS, int NSITES_T>
__device__ __forceinline__ void gemm_body(
    const ushort_t* __restrict__ xt, const ushort_t* __restrict__ wt,
    const float* __restrict__ bias, float* __restrict__ out,
    float* __restrict__ stats, char* ldsX, int bn, int bm) {
  const int tid = threadIdx.x;
  const int n0 = bn << 7;
  const int n_img = bm >> 3;
  const int h0p = (bm & 7) << 2;        // first padded x_t row of footprint
  const int wv = tid >> 6, lane = tid & 63;
  const int ri = lane & 15, kg = lane >> 4;
  const int wm = (wv & 1) << 6, wn = (wv >> 1) << 6;

  constexpr int XTOT = NSITES_T * 8;    // 16B loads for X footprint
  constexpr int XFP = XTOT / 256;       // full 256-thread passes
  constexpr int XTL = XTOT - XFP * 256; // tail threads

  // ---- X staging pointers (XOR swizzle at issue) ----
  const char* xgp[XFP + 1];
  char* xlp[XFP + 1];
  {
    const char* xg = (const char*)(xt + (size_t)(n_img * 34 + h0p) * (34 * 512));
#pragma unroll
    for (int p = 0; p < XFP + 1; ++p) {
      const int idx = p * 256 + tid;
      const int site = idx >> 3, slot = idx & 7;
      const int c = slot ^ (site & 7);
      xgp[p] = xg + site * 1024 + (c << 4);
      xlp[p] = ldsX + idx * 16;
    }
  }
  // ---- W fragment-major per-lane base pointers (coalesced 1KB/wave) ----
  const int g0 = (n0 + wn) >> 4;
  const char* wp[4];
#pragma unroll
  for (int f = 0; f < 4; ++f)
    wp[f] = (const char*)wt + (size_t)(g0 + f) * 147456 + (kg << 8) + (ri << 4);

  floatx4 acc[4][4] = {};
  short8 aw[2][2][4];                   // [buf][ks][f] — static idx only

  int bsite[4];
#pragma unroll
  for (int fj = 0; fj < 4; ++fj)
    bsite[fj] = ((wm >> 5) + (fj >> 1)) * 34 + ((fj & 1) << 4) + ri;

  for (int chunk = 0; chunk < 8; ++chunk) {
    const int cb = chunk << 7;          // X byte offset within tap row
    const int cw = chunk << 11;         // W byte offset (chunk*2048)
    // issue tap0's W loads first: latency hides under barrier + X DMA
#pragma unroll
    for (int ks = 0; ks < 2; ++ks)
#pragma unroll
      for (int f = 0; f < 4; ++f)
        aw[0][ks][f] = *(const short8*)(wp[f] + cw + (ks << 10));
    __syncthreads();   // WAR: all waves done reading previous chunk's X
#pragma unroll
    for (int p = 0; p < XFP; ++p) ASYNC16(xgp[p] + cb, xlp[p]);
    if (tid < XTL) ASYNC16(xgp[XFP] + cb, xlp[XFP]);   // tail
    __syncthreads();   // implicit vmcnt(0) drain: X resident & visible
#pragma unroll
    for (int tap = 0; tap < NTAPS; ++tap) {
      // prefetch tap+1's A-frags into the other register buffer
      if (tap + 1 < NTAPS) {
        const int noff = ((tap + 1) * 16384) + cw;
#pragma unroll
        for (int ks = 0; ks < 2; ++ks)
#pragma unroll
          for (int f = 0; f < 4; ++f)
            aw[(tap + 1) & 1][ks][f] =
                *(const short8*)(wp[f] + noff + (ks << 10));
      }
      const int tsite = (tap / 3) * 34 + (tap % 3);   // X site offset of tap
#pragma unroll
      for (int ks = 0; ks < 2; ++ks) {
        const int c = (ks << 2) + kg;    // 16B chunk index within row
        short8 b4[4];
#pragma unroll
        for (int fj = 0; fj < 4; ++fj) {
          const int srow = bsite[fj] + tsite;   // shifted site; swizzle on it
          b4[fj] = *(const short8*)(ldsX + srow * 128 + ((c ^ (srow & 7)) << 4));
        }
#pragma unroll
        for (int fi = 0; fi < 4; ++fi)
#pragma unroll
          for (int fj = 0; fj < 4; ++fj)
            acc[fi][fj] = __builtin_amdgcn_mfma_f32_16x16x32_bf16(
                aw[tap & 1][ks][fi], b4[fj], acc[fi][fj], 0, 0, 0);
      }
    }
  }

  // ---- epilogue: +bias, dense 2x2 pixel-shuffle writes, fused BN stats ----
  // D layout: col=lane&15 (m), row=quad*4+reg (n). Pair-interleaved rows:
  // (j0,j1) = same co, cols 2w/2w+1 -> contiguous floatx2; (j2,j3) = co+1.
  // Output row parity: P0 (bn<4) -> even rows; P1 -> odd rows.
  const int quad = kg, colL = ri;
  const int dh6 = (bn >> 2) << 6;       // +64 floats for odd output rows
#pragma unroll
  for (int fi = 0; fi < 4; ++fi) {
    const int rbase = n0 + wn + (fi << 4) + (quad << 2);   // global row', j=0..3
    const floatx4 bv = *(const floatx4*)(bias + rbase);
    const int co = (rbase & 511) >> 1;
    float sA = 0.f, s2A = 0.f, sB = 0.f, s2B = 0.f;
    float* ob = out + (((size_t)(n_img * 256 + co)) << 12) + dh6;
#pragma unroll
    for (int fj = 0; fj < 4; ++fj) {
      const int mb = wm + (fj << 4) + colL;       // m within block
      const int h = h0p + (mb >> 5), w = mb & 31; // global h (0..31)
      const float v0 = acc[fi][fj][0] + bv[0];
      const float v1 = acc[fi][fj][1] + bv[1];
      const float v2 = acc[fi][fj][2] + bv[2];
      const float v3 = acc[fi][fj][3] + bv[3];
      sA += v0 + v1;
      s2A += v0 * v0 + v1 * v1;
      sB += v2 + v3;
      s2B += v2 * v2 + v3 * v3;
      float* p = ob + (h << 7) + (w << 1);        // row 2h(+dh), col 2w
      floatx2 eA = {v0, v1};
      floatx2 eB = {v2, v3};
      *(floatx2*)p = eA;                           // co
      *(floatx2*)(p + 4096) = eB;                  // co+1
    }
#pragma unroll
    for (int off = 1; off < 16; off <<= 1) {
      sA += __shfl_xor(sA, off);
      s2A += __shfl_xor(s2A, off);
      sB += __shfl_xor(sB, off);
      s2B += __shfl_xor(s2B, off);
    }
    if (colL == 0) {
      atomicAdd(&stats[co], sA);
      atomicAdd(&stats[256 + co], s2A);
      atomicAdd(&stats[co + 1], sB);
      atomicAdd(&stats[256 + co + 1], s2B);
    }
  }
}

__global__ __launch_bounds__(256, 2) void gemm_kernel(
    const ushort_t* __restrict__ xt, const ushort_t* __restrict__ wt,
    const float* __restrict__ bias, float* __restrict__ out,
    float* __restrict__ stats) {
  // LDS: X only (26,112 B).
  __shared__ char ldsX[NSITES_P0 * 128];
  const int bx = blockIdx.x;
  // Panel flip at the grid midpoint: each XCD (bx&7 under round-robin
  // dispatch) runs 64 blocks of panel k, then 64 of panel k^4 -> per-XCD
  // 9-tap/6-tap totals balanced; <=2 W panels live per XCD L2 (panel
  // residency now serves the A-operand reads directly).
  const int bn = (bx & 7) ^ (((bx >> 9) & 1) << 2);
  const int bm = (bx >> 3) & 127;
  if (bn < 4)
    gemm_body<9, NSITES_P0>(xt, wt, bias, out, stats, ldsX, bn, bm);
  else
    gemm_body<6, NSITES_P1>(xt, wt, bias, out, stats, ldsX, bn, bm);
}

// -------------------------------------------------------------- bn_apply ---
__global__ __launch_bounds__(256) void bn_apply(
    float* __restrict__ y, const float* __restrict__ stats,
    const float* __restrict__ gamma, const float* __restrict__ beta) {
  const int b = blockIdx.x;
  const int co = b & 255;
  const int t = threadIdx.x;
  const float mean = stats[co] * (1.f / 65536.f);
  const float var = stats[256 + co] * (1.f / 65536.f) - mean * mean;
  const float rstd = rsqrtf(var + 1e-5f);
  const float scale = rstd * gamma[co];
  const float shift = beta[co] - mean * scale;
  float* p = y + (size_t)b * 4096;
#pragma unroll
  for (int it = 0; it < 4; ++it) {
    floatx4* q = (floatx4*)(p + (it * 256 + t) * 4);
    floatx4 v = *q;
#pragma unroll
    for (int e = 0; e < 4; ++e) v[e] = fmaxf(v[e] * scale + shift, 0.f);
    *q = v;
  }
}

// ---------------------------------------------------------------- launch ---
extern "C" void kernel_launch(void* const* d_in, const int* in_sizes, int n_in,
                              void* d_out, int out_size, void* d_ws,
                              size_t ws_size, hipStream_t stream) {
  const float* x  = (const float*)d_in[0];
  const float* w1 = (const float*)d_in[1];
  const float* b1 = (const float*)d_in[2];
  const float* w2 = (const float*)d_in[3];
  const float* b2 = (const float*)d_in[4];
  const float* w3 = (const float*)d_in[5];
  const float* b3 = (const float*)d_in[6];
  const float* w4 = (const float*)d_in[7];
  const float* b4 = (const float*)d_in[8];
  const float* gamma = (const float*)d_in[9];
  const float* beta  = (const float*)d_in[10];
  float* out = (float*)d_out;

  char* ws = (char*)d_ws;
  ushort_t* xt   = (ushort_t*)(ws + XT_OFF);
  ushort_t* wt   = (ushort_t*)(ws + WT_OFF);
  float*    bias = (float*)(ws + BIAS_OFF);
  float*    st   = (float*)(ws + STATS_OFF);

  prep_all<<<3200, 256, 0, stream>>>(x, xt, w1, w2, w3, w4,
                                     b1, b2, b3, b4, wt, bias, st);
  gemm_kernel<<<1024, 256, 0, stream>>>(xt, wt, bias, out, st);
  bn_apply<<<4096, 256, 0, stream>>>(out, st, gamma, beta);
}

// Round 15
// 264.467 us; speedup vs baseline: 1.8896x; 1.1702x over previous
//
#include <hip/hip_runtime.h>
#include <hip/hip_bf16.h>

// FastUpConvolution on MI355X — round 22: VERBATIM revert to R18 (verified
// best: 258.7us total, gemm ~142us). R21's asm-pinned W-from-L2 pipeline
// crashed the bench container twice (infra vs kernel-fault ambiguous); per
// pre-registration the W-from-L2 branch is closed after 3 attempts:
//   R19: L2 thrash (ri on row index, FETCH 208MB)
//   R20: compiler sank the C-level reg double-buffer (VGPR=108, 179us)
//   R21: container crash (asm global_load + manual waitcnt)
// Branch ledger for the gemm plateau (~142us, MfmaUtil 39):
//   - bigger tiles (R11 256m, R17 pair-fuse): occupancy/locality collapse
//   - deeper W pipeline (R13-16): works (R16) but only ~5us — barrier drain
//     was not the main stall; LDS port + latency diversity is.
//   - W direct from L2: closed (above).
//
// ws layout:
//   x_t   : bf16 [16][34][34][512]  @ 0          (18,939,904 B)
//   W_t   : bf16 [1024 rows][9*512] @ 18,939,904 ( 9,437,184 B)  row=pair-ilv
//   bias  : f32  [1024]             @ 28,377,088 (     4,096 B)  row=pair-ilv
//   stats : f32  [512] sum|sumsq    @ 28,381,184 (     2,048 B)
//
// Row layout: row' = ((q&1)<<9) + co*2 + (q>>1):
//   P0 rows 0..511   : q0 (3x3) s=0, q2 (3x2) s=1  -> even output rows, 9 taps
//   P1 rows 512..1023: q1 (2x3) s=0, q3 (2x2) s=1  -> odd output rows, 6 taps

typedef unsigned short ushort_t;
typedef __attribute__((ext_vector_type(8))) short short8;
typedef __attribute__((ext_vector_type(4))) float floatx4;
typedef __attribute__((ext_vector_type(2))) float floatx2;
typedef __attribute__((ext_vector_type(4))) unsigned short u16x4;
typedef __attribute__((ext_vector_type(8))) unsigned short u16x8;
typedef __attribute__((ext_vector_type(4))) unsigned int u32x4;

#define XT_OFF    0u
#define WT_OFF    18939904u
#define BIAS_OFF  28377088u
#define STATS_OFF 28381184u

#define NSITES_P0 204         // 6 rows x 34 cols X footprint, 128 B per site
#define NSITES_P1 170         // 5 rows x 34 cols (taps 0..5 only)

#define ASYNC16(g, l) __builtin_amdgcn_global_load_lds( \
    (const __attribute__((address_space(1))) void*)(g), \
    (__attribute__((address_space(3))) void*)(l), 16, 0, 0)

// Zero-instruction compiler fence: pins emission order of memory intrinsics
// (vmcnt counts in emission order; counted waits depend on it).
#define ISSUE_FENCE asm volatile("" ::: "memory")

// Fused wait+barrier (R16-proven). vmcnt(4): own W prefetch stays in flight.
// lgkmcnt(0): all own LDS reads returned before the barrier (no WAR vs the
// next segment's DMA into the recycled buffer).
#define WAITBAR4 \
  asm volatile("s_waitcnt vmcnt(4) lgkmcnt(0)\n\ts_barrier" ::: "memory")
#define WAITBAR0 \
  asm volatile("s_waitcnt vmcnt(0) lgkmcnt(0)\n\ts_barrier" ::: "memory")

__device__ __forceinline__ ushort_t f2bf(float f) {
  unsigned int u = __builtin_bit_cast(unsigned int, f);
  u += 0x7fffu + ((u >> 16) & 1u);   // RNE (values finite here)
  return (ushort_t)(u >> 16);
}

// --------------------------------------------------------------- prep_all --
// Blocks 0..1023: W prep (block 0 also zeroes stats).
// Blocks 1024..3199: X prep, one block per (n, hp, ci-quarter):
//   x[16][512][32][32] f32 -> x_t[16][34][34][512] bf16, zero-padded NHWC.
__global__ __launch_bounds__(256) void prep_all(
    const float* __restrict__ x, ushort_t* __restrict__ xt,
    const float* __restrict__ w1, const float* __restrict__ w2,
    const float* __restrict__ w3, const float* __restrict__ w4,
    const float* __restrict__ b1, const float* __restrict__ b2,
    const float* __restrict__ b3, const float* __restrict__ b4,
    ushort_t* __restrict__ wt, float* __restrict__ bias,
    float* __restrict__ stats) {
  __shared__ ushort_t lds[128 * 36];   // 9,216 B
  const int blk = blockIdx.x;
  const int t = threadIdx.x;
  if (blk < 1024) {
    // ---------------- W prep ----------------
    const int q = blk >> 8, co = blk & 255;
    const int row = ((q & 1) << 9) + (co << 1) + (q >> 1);  // pair-interleaved
    if (blk == 0) { stats[t] = 0.f; stats[t + 256] = 0.f; }
    const float* wsrc; const float* bsrc; int khl, kwl;
    if (q == 0)      { wsrc = w1; bsrc = b1; khl = 3; kwl = 3; }
    else if (q == 1) { wsrc = w2; bsrc = b2; khl = 2; kwl = 3; }
    else if (q == 2) { wsrc = w3; bsrc = b3; khl = 3; kwl = 2; }
    else             { wsrc = w4; bsrc = b4; khl = 2; kwl = 2; }
    if (t == 0) bias[row] = bsrc[co];
    ushort_t* dst = wt + (size_t)row * 4608;
    for (int tap = 0; tap < 9; ++tap) {
      const int dh = tap / 3, dw = tap % 3;
      const bool valid = (dh < khl) && (dw < kwl);
#pragma unroll
      for (int cc = 0; cc < 2; ++cc) {
        const int ci = cc * 256 + t;
        ushort_t v = 0;
        if (valid)
          v = f2bf(wsrc[(((size_t)co * 512 + ci) * khl + dh) * kwl + dw]);
        dst[tap * 512 + ci] = v;
      }
    }
    return;
  }
  // ---------------- X prep (quarter) ----------------
  const int idx = blk - 1024;
  const int n = idx / 136;            // 136 = 34 hp * 4 quarters
  const int rem = idx % 136;
  const int hp = rem >> 2;
  const int ci0 = (rem & 3) << 7;     // 0,128,256,384
  ushort_t* dst = xt + (size_t)(n * 34 + hp) * (34 * 512);
  if (hp == 0 || hp == 33) {
    u32x4 z = {0u, 0u, 0u, 0u};
    for (int i = t; i < 544; i += 256)
      ((u32x4*)(dst + (i >> 4) * 512 + ci0))[i & 15] = z;
    return;
  }
  const int h = hp - 1;
  if (t < 32) {
    u32x4 z = {0u, 0u, 0u, 0u};
    const int w = (t >> 4) ? 33 : 0;
    ((u32x4*)(dst + w * 512 + ci0))[t & 15] = z;
  }
  const size_t base = (size_t)n * 524288 + (size_t)h * 32;
  {
    const int cil = t >> 3;
    const int w4 = (t & 7) << 2;
#pragma unroll
    for (int cc = 0; cc < 4; ++cc) {
      const int ci = cil + cc * 32;
      floatx4 v = *(const floatx4*)(x + base + (size_t)(ci0 + ci) * 1024 + w4);
      u16x4 hv;
#pragma unroll
      for (int j = 0; j < 4; ++j) hv[j] = f2bf(v[j]);
      *(u16x4*)&lds[ci * 36 + w4] = hv;
    }
  }
  __syncthreads();
  {
    const int w = t & 31;
    const int j8 = t >> 5;
#pragma unroll
    for (int cc2 = 0; cc2 < 2; ++cc2) {
      const int cil2 = cc2 * 64 + j8 * 8;
      u16x8 v;
#pragma unroll
      for (int j = 0; j < 8; ++j) v[j] = lds[(cil2 + j) * 36 + w];
      *(u16x8*)(dst + (w + 1) * 512 + ci0 + cil2) = v;
    }
  }
}

// ------------------------------------------------------------- gemm body ---
// (VERBATIM R16.) Block 128 m (4h x 32w) x 128 n (one quadrant-pair);
// 4 waves 2x2, 4x4 frags of 16x16x32 bf16. K = 8 chunks x 64 ci x NTAPS
// (compile-time: P0 9, P1 6). Per chunk: stage X | fence | W0->wb0 | fence |
// W1->wb1, fused {vmcnt(4) lgkm(0); barrier}. Per tap t: issue W(t+2) into
// wb[(t+2)%3]; 2 k-steps x 16 MFMA on wb[t%3]; fused wait+bar.
// LDS unpadded, XOR-swizzled: 16B chunk c of row r at slot c^(r&7).
template <int NTAPS, int NSITES_T>
__device__ __forceinline__ void gemm_body(
    const ushort_t* __restrict__ xt, const ushort_t* __restrict__ wt,
    const float* __restrict__ bias, float* __restrict__ out,
    float* __restrict__ stats, char* ldsX, char* ldsW,
    int bn, int bm) {
  const int tid = threadIdx.x;
  const int n0 = bn << 7;
  const int n_img = bm >> 3;
  const int h0p = (bm & 7) << 2;        // first padded x_t row of footprint
  const int wv = tid >> 6, lane = tid & 63;
  const int ri = lane & 15, kg = lane >> 4;
  const int wm = (wv & 1) << 6, wn = (wv >> 1) << 6;

  constexpr int XTOT = NSITES_T * 8;    // 16B loads for X footprint
  constexpr int XFP = XTOT / 256;       // full 256-thread passes
  constexpr int XTL = XTOT - XFP * 256; // tail threads

  // ---- staging pointer precompute (XOR swizzle at issue) ----
  const char* xgp[XFP + 1];
  char* xlp[XFP + 1];
  {
    const char* xg = (const char*)(xt + (size_t)(n_img * 34 + h0p) * (34 * 512));
#pragma unroll
    for (int p = 0; p < XFP + 1; ++p) {
      const int idx = p * 256 + tid;
      const int site = idx >> 3, slot = idx & 7;
      const int c = slot ^ (site & 7);
      xgp[p] = xg + site * 1024 + (c << 4);
      xlp[p] = ldsX + idx * 16;
    }
  }
  // W: idx = p*256+tid over 1024 = 128 rows x 8 slots; 3 LDS buffers.
  const char* wgp[4];
#pragma unroll
  for (int p = 0; p < 4; ++p) {
    const int idx = p * 256 + tid;
    const int row = idx >> 3, slot = idx & 7;
    const int c = slot ^ (row & 7);
    wgp[p] = (const char*)wt + (size_t)(n0 + row) * 9216 + (c << 4);
  }
  char* const wl = ldsW + tid * 16;     // + buf*16384 + p*4096

  floatx4 acc[4][4] = {};

  // fragment row/site indices
  int arow[4], bsite[4];
#pragma unroll
  for (int f = 0; f < 4; ++f) arow[f] = wn + (f << 4) + ri;
#pragma unroll
  for (int fj = 0; fj < 4; ++fj)
    bsite[fj] = ((wm >> 5) + (fj >> 1)) * 34 + ((fj & 1) << 4) + ri;

  for (int chunk = 0; chunk < 8; ++chunk) {
    const int cb = chunk << 7;
    // ---- chunk prologue: stage X | fence | W0 | fence | W1 ----
    // (ldsX / wb0 / wb1 readers all finished — data returned — before the
    //  last-tap barrier of the previous chunk, which drained vm+lgkm to 0.)
#pragma unroll
    for (int p = 0; p < XFP; ++p) ASYNC16(xgp[p] + cb, xlp[p]);
    if (tid < XTL) ASYNC16(xgp[XFP] + cb, xlp[XFP]);   // tail
    ISSUE_FENCE;   // X emitted before W0 (vmcnt counts in emission order)
#pragma unroll
    for (int p = 0; p < 4; ++p) ASYNC16(wgp[p] + cb, wl + p * 4096);
    ISSUE_FENCE;   // W0 emitted before W1 -> "newest 4" at the wait == W1
#pragma unroll
    for (int p = 0; p < 4; ++p)
      ASYNC16(wgp[p] + cb + 1024, wl + 16384 + p * 4096);
    WAITBAR4;                            // X + W0 landed; W1's 4 in flight
#pragma unroll
    for (int tap = 0; tap < NTAPS; ++tap) {
      // prefetch W(tap+2) into wb[(tap+2)%3] (readers of that buffer were
      // tap-1; their ds_reads RETURNED before tap-1's fused barrier)
      if (tap + 2 < NTAPS) {
        const int noff = ((tap + 2) << 10) + cb;
        char* const wld = ldsW + ((tap + 2) % 3) * 16384 + tid * 16;
#pragma unroll
        for (int p = 0; p < 4; ++p) ASYNC16(wgp[p] + noff, wld + p * 4096);
      }
      const char* wb = ldsW + (tap % 3) * 16384;
      const int tsite = (tap / 3) * 34 + (tap % 3);   // X site offset of tap
#pragma unroll
      for (int ks = 0; ks < 2; ++ks) {
        const int c = (ks << 2) + kg;    // 16B chunk index within row
        short8 a4[4], b4[4];
#pragma unroll
        for (int f = 0; f < 4; ++f)
          a4[f] = *(const short8*)(wb + arow[f] * 128 +
                                   ((c ^ (arow[f] & 7)) << 4));
#pragma unroll
        for (int fj = 0; fj < 4; ++fj) {
          const int srow = bsite[fj] + tsite;   // shifted site; swizzle on it
          b4[fj] = *(const short8*)(ldsX + srow * 128 + ((c ^ (srow & 7)) << 4));
        }
#pragma unroll
        for (int fi = 0; fi < 4; ++fi)
#pragma unroll
          for (int fj = 0; fj < 4; ++fj)
            acc[fi][fj] = __builtin_amdgcn_mfma_f32_16x16x32_bf16(
                a4[fi], b4[fj], acc[fi][fj], 0, 0, 0);
      }
      // end-of-tap sync: W(tap+1) resident for next tap (vmcnt<=4); own
      // ds_reads all returned (lgkmcnt 0); W(tap+2) crosses in flight.
      if (tap + 2 < NTAPS) { WAITBAR4; } else { WAITBAR0; }
    }
  }

  // ---- epilogue: +bias, dense 2x2 pixel-shuffle writes, fused BN stats ----
  // D layout: col=lane&15 (m), row=quad*4+reg (n). Pair-interleaved rows:
  // (j0,j1) = same co, cols 2w/2w+1 -> contiguous floatx2; (j2,j3) = co+1.
  // Output row parity: P0 (bn<4) -> even rows; P1 -> odd rows.
  const int quad = kg, colL = ri;
  const int dh6 = (bn >> 2) << 6;       // +64 floats for odd output rows
#pragma unroll
  for (int fi = 0; fi < 4; ++fi) {
    const int rbase = n0 + wn + (fi << 4) + (quad << 2);   // global row', j=0..3
    const floatx4 bv = *(const floatx4*)(bias + rbase);
    const int co = (rbase & 511) >> 1;
    float sA = 0.f, s2A = 0.f, sB = 0.f, s2B = 0.f;
    float* ob = out + (((size_t)(n_img * 256 + co)) << 12) + dh6;
#pragma unroll
    for (int fj = 0; fj < 4; ++fj) {
      const int mb = wm + (fj << 4) + colL;       // m within block
      const int h = h0p + (mb >> 5), w = mb & 31; // global h (0..31)
      const float v0 = acc[fi][fj][0] + bv[0];
      const float v1 = acc[fi][fj][1] + bv[1];
      const float v2 = acc[fi][fj][2] + bv[2];
      const float v3 = acc[fi][fj][3] + bv[3];
      sA += v0 + v1;
      s2A += v0 * v0 + v1 * v1;
      sB += v2 + v3;
      s2B += v2 * v2 + v3 * v3;
      float* p = ob + (h << 7) + (w << 1);        // row 2h(+dh), col 2w
      floatx2 eA = {v0, v1};
      floatx2 eB = {v2, v3};
      *(floatx2*)p = eA;                           // co
      *(floatx2*)(p + 4096) = eB;                  // co+1
    }
#pragma unroll
    for (int off = 1; off < 16; off <<= 1) {
      sA += __shfl_xor(sA, off);
      s2A += __shfl_xor(s2A, off);
      sB += __shfl_xor(sB, off);
      s2B += __shfl_xor(s2B, off);
    }
    if (colL == 0) {
      atomicAdd(&stats[co], sA);
      atomicAdd(&stats[256 + co], s2A);
      atomicAdd(&stats[co + 1], sB);
      atomicAdd(&stats[256 + co + 1], s2B);
    }
  }
}

__global__ __launch_bounds__(256) void gemm_kernel(
    const ushort_t* __restrict__ xt, const ushort_t* __restrict__ wt,
    const float* __restrict__ bias, float* __restrict__ out,
    float* __restrict__ stats) {
  // LDS declared once, shared by both instantiations (75,264 B total
  // -> still 2 blocks/CU).
  __shared__ char ldsX[NSITES_P0 * 128]; // 26,112 B
  __shared__ char ldsW[3][128 * 128];    // 3 x 16,384 B (triple buffer)
  const int bx = blockIdx.x;
  // Panel flip at the grid midpoint: each XCD (bx&7 under round-robin
  // dispatch) runs 64 blocks of panel k, then 64 of panel k^4 -> per-XCD
  // 9-tap/6-tap totals balanced; <=2 W panels live per XCD L2.
  const int bn = (bx & 7) ^ (((bx >> 9) & 1) << 2);
  const int bm = (bx >> 3) & 127;
  if (bn < 4)
    gemm_body<9, NSITES_P0>(xt, wt, bias, out, stats,
                            ldsX, ldsW[0], bn, bm);
  else
    gemm_body<6, NSITES_P1>(xt, wt, bias, out, stats,
                            ldsX, ldsW[0], bn, bm);
}

// -------------------------------------------------------------- bn_apply ---
__global__ __launch_bounds__(256) void bn_apply(
    float* __restrict__ y, const float* __restrict__ stats,
    const float* __restrict__ gamma, const float* __restrict__ beta) {
  const int b = blockIdx.x;
  const int co = b & 255;
  const int t = threadIdx.x;
  const float mean = stats[co] * (1.f / 65536.f);
  const float var = stats[256 + co] * (1.f / 65536.f) - mean * mean;
  const float rstd = rsqrtf(var + 1e-5f);
  const float scale = rstd * gamma[co];
  const float shift = beta[co] - mean * scale;
  float* p = y + (size_t)b * 4096;
#pragma unroll
  for (int it = 0; it < 4; ++it) {
    floatx4* q = (floatx4*)(p + (it * 256 + t) * 4);
    floatx4 v = *q;
#pragma unroll
    for (int e = 0; e < 4; ++e) v[e] = fmaxf(v[e] * scale + shift, 0.f);
    *q = v;
  }
}

// ---------------------------------------------------------------- launch ---
extern "C" void kernel_launch(void* const* d_in, const int* in_sizes, int n_in,
                              void* d_out, int out_size, void* d_ws,
                              size_t ws_size, hipStream_t stream) {
  const float* x  = (const float*)d_in[0];
  const float* w1 = (const float*)d_in[1];
  const float* b1 = (const float*)d_in[2];
  const float* w2 = (const float*)d_in[3];
  const float* b2 = (const float*)d_in[4];
  const float* w3 = (const float*)d_in[5];
  const float* b3 = (const float*)d_in[6];
  const float* w4 = (const float*)d_in[7];
  const float* b4 = (const float*)d_in[8];
  const float* gamma = (const float*)d_in[9];
  const float* beta  = (const float*)d_in[10];
  float* out = (float*)d_out;

  char* ws = (char*)d_ws;
  ushort_t* xt   = (ushort_t*)(ws + XT_OFF);
  ushort_t* wt   = (ushort_t*)(ws + WT_OFF);
  float*    bias = (float*)(ws + BIAS_OFF);
  float*    st   = (float*)(ws + STATS_OFF);

  prep_all<<<3200, 256, 0, stream>>>(x, xt, w1, w2, w3, w4,
                                     b1, b2, b3, b4, wt, bias, st);
  gemm_kernel<<<1024, 256, 0, stream>>>(xt, wt, bias, out, st);
  bn_apply<<<4096, 256, 0, stream>>>(out, st, gamma, beta);
}